// Round 4
// baseline (355.667 us; speedup 1.0000x reference)
//
#include <hip/hip_runtime.h>

// out[row] = (sum_{f<1024} x[row,f]) * (sum coeffs), rows = 16*4096 = 65536.
// Pure streaming reduction: 256 MiB read, 256 KiB write -> HBM-bound,
// floor ~41 us at 6.5 TB/s achievable.
//
// 2048 blocks x 256 threads = 8192 waves (8 blocks/CU, 32 waves/CU).
// Each wave handles consecutive row-pairs (2p, 2p+1), p = w + i*8192:
// 8 KiB contiguous per wave-iteration, 32 KiB per block -> good DRAM page
// locality. PLAIN loads (no nontemporal: nt bypasses L2 and measured ~half
// of the 6.5 TB/s the harness's own fills reach; m13's 6.29 TB/s copy
// ceiling used plain loads).

#define WAVES_PER_BLOCK 4
#define NUM_BLOCKS 2048

__global__ __launch_bounds__(256) void spline_rowsum_kernel(
    const float* __restrict__ x,
    const float* __restrict__ coeffs,
    float* __restrict__ out,
    int nrows) {
  const int lane = threadIdx.x & 63;
  const int w = blockIdx.x * WAVES_PER_BLOCK + (threadIdx.x >> 6);
  const int total_waves = NUM_BLOCKS * WAVES_PER_BLOCK;  // 8192

  float cs = 0.0f;
#pragma unroll
  for (int k = 0; k < 10; ++k) cs += coeffs[k];  // scalar, L2-resident

  const int npairs = nrows >> 1;  // 32768
  for (int p = w; p < npairs; p += total_waves) {
    const int r = p << 1;  // rows r, r+1: 8 KiB contiguous
    const float4* xa = reinterpret_cast<const float4*>(
                           x + (long long)r * 1024) + lane;

    // 8 independent 16B loads in flight (2 KiB of the 8 KiB pair per lane set)
    float4 a0 = xa[0 * 64];
    float4 a1 = xa[1 * 64];
    float4 a2 = xa[2 * 64];
    float4 a3 = xa[3 * 64];
    float4 b0 = xa[4 * 64];
    float4 b1 = xa[5 * 64];
    float4 b2 = xa[6 * 64];
    float4 b3 = xa[7 * 64];

    float sa = ((a0.x + a0.y) + (a0.z + a0.w)) + ((a1.x + a1.y) + (a1.z + a1.w))
             + ((a2.x + a2.y) + (a2.z + a2.w)) + ((a3.x + a3.y) + (a3.z + a3.w));
    float sb = ((b0.x + b0.y) + (b0.z + b0.w)) + ((b1.x + b1.y) + (b1.z + b1.w))
             + ((b2.x + b2.y) + (b2.z + b2.w)) + ((b3.x + b3.y) + (b3.z + b3.w));

#pragma unroll
    for (int off = 32; off > 0; off >>= 1) {
      sa += __shfl_down(sa, off, 64);
      sb += __shfl_down(sb, off, 64);
    }
    if (lane == 0) {
      out[r] = sa * cs;
      out[r + 1] = sb * cs;
    }
  }
}

extern "C" void kernel_launch(void* const* d_in, const int* in_sizes, int n_in,
                              void* d_out, int out_size, void* d_ws, size_t ws_size,
                              hipStream_t stream) {
  const float* x      = (const float*)d_in[0];   // 16*4096*1024 fp32
  const float* coeffs = (const float*)d_in[1];   // 10 fp32
  float* out          = (float*)d_out;           // 65536 fp32

  spline_rowsum_kernel<<<NUM_BLOCKS, 256, 0, stream>>>(x, coeffs, out, out_size);
}